// Round 11
// baseline (1018.781 us; speedup 1.0000x reference)
//
#include <hip/hip_runtime.h>
#include <math.h>

// NNFM loss on MI355X.
// loss = mean_i (1 - max_j (xhat_i . shat_j)),  xhat/shat = column-normalized feats.
// R2: XOR-swizzle -> 0 conflicts. R5: fp8 BK=128. R7: i8 16x16x64.
// R8: 128^2 4-wave, 2 blocks/CU overlap -> 239us. R9: merged phase (neutral).
// R10: XCD L2-residency map -> FETCH 740->56MB, GEMM 180us (MFMA 104us | LDS 123us floors).
// R11: A direct global->VGPR from L2 (fragment-linear Xn layout written by tnorm):
//      LDS reads halve (61us floor), LDS 32KB (B only) -> 4 blocks/CU (JSPLIT=8).

#define C_DIM 768
#define P_DIM 16384
#define KT 6            // K-tiles (BK=128) : 768/128
#define NJT 16          // j-tiles per block: 2048/128
#define JSPLIT 8
#define EPSF 1e-8f
#define QSCALE 256.0f

typedef unsigned char u8;
typedef int i32x4 __attribute__((ext_vector_type(4)));

// workspace layout (bytes); high-water 50987008 (== R2-proven)
#define OFF_XN   0
#define OFF_SN   25165824UL
#define OFF_INVX 50331648UL
#define OFF_INVS 50397184UL
#define OFF_MAX  50462720UL                 // 8 * 16384 * 4

__device__ __forceinline__ void async_copy16(const void* gsrc, void* ldst) {
    __builtin_amdgcn_global_load_lds(
        (const __attribute__((address_space(1))) void*)gsrc,
        (__attribute__((address_space(3))) void*)ldst,
        16, 0, 0);
}

#define CFENCE() asm volatile("" ::: "memory")
#define BARRIER() { CFENCE(); __builtin_amdgcn_s_barrier(); CFENCE(); }

// --- 1. column L2 norms: inv = QSCALE/(||col|| + eps); one thread per column ---
__global__ void norm_kernel(const float* __restrict__ x, const float* __restrict__ s,
                            float* __restrict__ invx, float* __restrict__ invs) {
    const float* src = blockIdx.y == 0 ? x : s;
    float* dst = (blockIdx.y == 0) ? invx : invs;
    int j = blockIdx.x * 256 + threadIdx.x;        // 0..16383
    float sum = 0.f;
    for (int c = 0; c < C_DIM; ++c) {
        float v = src[(size_t)c * P_DIM + j];
        sum += v * v;
    }
    dst[j] = QSCALE / (sqrtf(sum) + EPSF);
}

// --- 2. transpose, normalize*256, round to int8 ---
// Sn (z=1): row-major [p][c] (DMA->LDS path, as R7-R10).
// Xn (z=0): fragment-linear for direct global->VGPR MFMA A-operands:
//   byte addr = (((kt*1024 + g)*2 + ks)*1024) + lane*16 + byteoff
//   where g = row>>4, lane = (kb>>4)*16 + (row&15), kb = channel offset within
//   the 64-ch half-tile (ks), byteoff = kb&15. One 1KB chunk per (kt,g,ks) is
//   exactly one wave's coalesced global_load_dwordx4.
__global__ void tnorm_kernel(const float* __restrict__ x, const float* __restrict__ s,
                             const float* __restrict__ invx, const float* __restrict__ invs,
                             u8* __restrict__ Xn, u8* __restrict__ Sn) {
    __shared__ float tile[64][65];
    const float* src = blockIdx.z ? s : x;
    const float* inv = blockIdx.z ? invs : invx;
    u8* dst = blockIdx.z ? Sn : Xn;
    int c0 = blockIdx.y * 64;
    int j0 = blockIdx.x * 64;
    int t = threadIdx.x;
    #pragma unroll
    for (int it = 0; it < 16; ++it) {
        int idx = it * 256 + t;
        int cr = idx >> 6, jc = idx & 63;
        tile[cr][jc] = src[(c0 + cr) * P_DIM + j0 + jc];
    }
    __syncthreads();
    const int kt = c0 >> 7;
    const int ks = (c0 >> 6) & 1;
    #pragma unroll
    for (int it = 0; it < 2; ++it) {
        int item = it * 256 + t;
        int jr = item >> 3;
        int oct = item & 7;
        float iv = inv[j0 + jr];
        unsigned long long pk = 0;
        #pragma unroll
        for (int o = 0; o < 8; ++o) {
            float v = tile[oct * 8 + o][jr] * iv;
            v = fminf(fmaxf(v, -127.0f), 127.0f);
            int q = (int)rintf(v);
            pk |= ((unsigned long long)(unsigned)(q & 0xFF)) << (8 * o);
        }
        size_t addr;
        if (blockIdx.z) {
            addr = (size_t)(j0 + jr) * C_DIM + c0 + oct * 8;
        } else {
            const int g = (j0 + jr) >> 4;
            const int lane = ((oct >> 1) << 4) + (jr & 15);
            addr = ((((size_t)kt * 1024 + g) * 2 + ks) << 10) + lane * 16 + ((oct & 1) << 3);
        }
        *(unsigned long long*)(dst + addr) = pk;
    }
}

// --- 3. 128x128-tile i8 GEMM: A direct from L2, B via LDS; 4 blocks/CU ---
// XCD map: xcd=bid&7 owns iblks [16x,16x+16) x all 8 splits -> A 1.5MB/XCD resident.
// Phase t: {ds_read bF(buf t) | issue 8 A(t) b128 loads | DMA B(t+2)->buf t |
//           vmcnt(4) lgkmcnt(0) [drains B(t+1)+A(t), keeps B(t+2)] | 32 MFMA | barrier}
__global__ __launch_bounds__(256, 4) void nnfm_gemm_max(
    const u8* __restrict__ Xn, const u8* __restrict__ Sn,
    float* __restrict__ wmax) {
    __shared__ __align__(16) u8 smB[2][128 * 128];

    const int bid = blockIdx.x;
    const int xcd = bid & 7;
    const int idx = bid >> 3;               // 0..127
    const int iblk = xcd * 16 + (idx & 15);
    const int split = idx >> 4;             // 0..7
    const int i0 = iblk * 128;
    const int jbase = split * (P_DIM / JSPLIT);

    const int tid = threadIdx.x;
    const int lane = tid & 63;
    const int wid = tid >> 6;
    const int wrow = (wid >> 1) * 64;
    const int wcol = (wid & 1) * 64;
    const int lm = lane & 15;

    const int srow = wid * 8 + (lane >> 3);                // staging row (+c*32)
    const int scol = ((lane & 7) ^ (lane >> 3)) * 16;      // swizzled source col
    const int kidx0 = (((lane >> 4) + 0) ^ (lane & 7)) * 16;
    const int kidx1 = (((lane >> 4) + 4) ^ (lane & 7)) * 16;

    // A fragment base: g = iblk*8 + wrow/16 + m ; addr = ((kt*1024+g)*2+ks)*1024 + lane*16
    const u8* Abase = Xn + ((((size_t)iblk * 8 + (wrow >> 4)) * 2) << 10) + lane * 16;

#define STAGE_B(jt_t, kk_t, buf_t) { \
    _Pragma("unroll") \
    for (int c = 0; c < 4; ++c) \
      async_copy16(Sn + (size_t)(jbase + (jt_t) * 128 + c * 32 + srow) * C_DIM + (kk_t) * 128 + scol, \
                   &smB[buf_t][(c * 32 + wid * 8) * 128]); }

#define RD_B(BUF) { \
    _Pragma("unroll") \
    for (int n = 0; n < 4; ++n) { \
      bF[n][0] = *(const i32x4*)&smB[BUF][(wcol + n * 16 + lm) * 128 + kidx0]; \
      bF[n][1] = *(const i32x4*)&smB[BUF][(wcol + n * 16 + lm) * 128 + kidx1]; \
    } }

#define LD_A(kt_t) { \
    _Pragma("unroll") \
    for (int m = 0; m < 4; ++m) { \
      aF[m][0] = *(const i32x4*)(Abase + ((((size_t)(kt_t) * 1024 + m) * 2 + 0) << 10)); \
      aF[m][1] = *(const i32x4*)(Abase + ((((size_t)(kt_t) * 1024 + m) * 2 + 1) << 10)); \
    } }

#define MFMA32(DOZERO) { \
    if (DOZERO) { \
      _Pragma("unroll") \
      for (int m = 0; m < 4; ++m) \
        _Pragma("unroll") \
        for (int n = 0; n < 4; ++n) \
          acc[m][n] = i32x4{0, 0, 0, 0}; \
    } \
    __builtin_amdgcn_s_setprio(1); \
    _Pragma("unroll") \
    for (int ks = 0; ks < 2; ++ks) \
      _Pragma("unroll") \
      for (int m = 0; m < 4; ++m) \
        _Pragma("unroll") \
        for (int n = 0; n < 4; ++n) \
          acc[m][n] = __builtin_amdgcn_mfma_i32_16x16x64_i8(aF[m][ks], bF[n][ks], acc[m][n], 0, 0, 0); \
    __builtin_amdgcn_s_setprio(0); }

    i32x4 acc[4][4];
    int rmax[4][4];
    i32x4 aF[4][2], bF[4][2];
    #pragma unroll
    for (int m = 0; m < 4; ++m)
        #pragma unroll
        for (int r = 0; r < 4; ++r) rmax[m][r] = (int)0x80000000;

    // prologue: B(0)->buf0, B(1)->buf1 (8 DMA); drain B(0) -> vmcnt(4)
    STAGE_B(0, 0, 0);
    STAGE_B(0, 1, 1);
    asm volatile("s_waitcnt vmcnt(4)" ::: "memory");
    BARRIER();

    for (int jt = 0; jt < NJT; ++jt) {
        for (int kk = 0; kk < KT; ++kk) {
            const int buf = kk & 1;
            int kk2 = kk + 2, jt2 = jt;
            if (kk2 >= KT) { kk2 -= KT; jt2 = (jt + 1) & (NJT - 1); }
            const bool z = (kk == 0), rx = (kk == KT - 1);

            RD_B(buf)
            LD_A(kk)
            STAGE_B(jt2, kk2, buf)            // into live buf after its reads
            asm volatile("s_waitcnt vmcnt(4) lgkmcnt(0)" ::: "memory");
            MFMA32(z)
            if (rx) {
                #pragma unroll
                for (int m = 0; m < 4; ++m)
                    #pragma unroll
                    for (int r = 0; r < 4; ++r) {
                        int mx = acc[m][0][r];
                        #pragma unroll
                        for (int n = 1; n < 4; ++n)
                            if (acc[m][n][r] > mx) mx = acc[m][n][r];
                        if (mx > rmax[m][r]) rmax[m][r] = mx;
                    }
            }
            BARRIER();
        }
    }

    // epilogue: drain all in-flight ops before reusing LDS
    asm volatile("s_waitcnt vmcnt(0) lgkmcnt(0)" ::: "memory");
    BARRIER();

    const float isc = 1.0f / (QSCALE * QSCALE);
    float* red = (float*)&smB[0][0];   // [2 col-waves][128 rows]
    #pragma unroll
    for (int m = 0; m < 4; ++m)
        #pragma unroll
        for (int r = 0; r < 4; ++r) {
            int v = rmax[m][r];
            int o;
            o = __shfl_xor(v, 1); if (o > v) v = o;
            o = __shfl_xor(v, 2); if (o > v) v = o;
            o = __shfl_xor(v, 4); if (o > v) v = o;
            o = __shfl_xor(v, 8); if (o > v) v = o;
            if (lm == 0) {
                const int row_l = wrow + m * 16 + (lane >> 4) * 4 + r;
                red[(wid & 1) * 128 + row_l] = (float)v * isc;
            }
        }
    BARRIER();
    if (tid < 128) {
        wmax[(size_t)split * P_DIM + i0 + tid] = fmaxf(red[tid], red[128 + tid]);
    }
}

// --- 4. loss = mean(1 - max over 8 partials) ---
__global__ void final_reduce(const float* __restrict__ wmax, float* __restrict__ out) {
    __shared__ float red[256];
    int t = threadIdx.x;
    float sum = 0.f;
    for (int i = t; i < P_DIM; i += 256) {
        float m = wmax[i];
        #pragma unroll
        for (int sp = 1; sp < 8; ++sp) m = fmaxf(m, wmax[(size_t)sp * P_DIM + i]);
        sum += 1.0f - m;
    }
    red[t] = sum;
    __syncthreads();
    for (int st = 128; st > 0; st >>= 1) {
        if (t < st) red[t] += red[t + st];
        __syncthreads();
    }
    if (t == 0) out[0] = red[0] * (1.0f / (float)P_DIM);
}

extern "C" void kernel_launch(void* const* d_in, const int* in_sizes, int n_in,
                              void* d_out, int out_size, void* d_ws, size_t ws_size,
                              hipStream_t stream) {
    const float* x = (const float*)d_in[0];
    const float* s = (const float*)d_in[1];
    float* out = (float*)d_out;
    char* ws = (char*)d_ws;

    u8* Xn = (u8*)(ws + OFF_XN);
    u8* Sn = (u8*)(ws + OFF_SN);
    float* invx = (float*)(ws + OFF_INVX);
    float* invs = (float*)(ws + OFF_INVS);
    float* wmax = (float*)(ws + OFF_MAX);

    norm_kernel<<<dim3(64, 2), 256, 0, stream>>>(x, s, invx, invs);
    tnorm_kernel<<<dim3(256, 12, 2), 256, 0, stream>>>(x, s, invx, invs, Xn, Sn);
    nnfm_gemm_max<<<dim3((P_DIM / 128) * JSPLIT), 256, 0, stream>>>(Xn, Sn, wmax);
    final_reduce<<<1, 256, 0, stream>>>(wmax, out);
}

// Round 12
// 310.488 us; speedup vs baseline: 3.2812x; 3.2812x over previous
//
#include <hip/hip_runtime.h>
#include <math.h>

// NNFM loss on MI355X.
// loss = mean_i (1 - max_j (xhat_i . shat_j)),  xhat/shat = column-normalized feats.
// R2: XOR-swizzle -> 0 conflicts. R5: fp8 BK=128. R7: i8 16x16x64.
// R8: 128^2 4-wave, 2 blocks/CU overlap -> 239us. R10: XCD L2-residency map ->
//     FETCH 740->56MB, GEMM 180us. R11: A direct from L2 + B-only LDS, but
//     launch_bounds(256,4) capped VGPR at 64 -> 1.7GB spill (layout verified, absmax 0).
// R12: R11 structure at launch_bounds(256,2), JSPLIT=4 (R10's proven residency map):
//      B-only LDS 32KB, A global->VGPR, halved LDS reads, no spill.

#define C_DIM 768
#define P_DIM 16384
#define KT 6            // K-tiles (BK=128) : 768/128
#define NJT 32          // j-tiles per block: 4096/128
#define JSPLIT 4
#define EPSF 1e-8f
#define QSCALE 256.0f

typedef unsigned char u8;
typedef int i32x4 __attribute__((ext_vector_type(4)));

// workspace layout (bytes)
#define OFF_XN   0
#define OFF_SN   25165824UL
#define OFF_INVX 50331648UL
#define OFF_INVS 50397184UL
#define OFF_MAX  50462720UL                 // 4 * 16384 * 4

__device__ __forceinline__ void async_copy16(const void* gsrc, void* ldst) {
    __builtin_amdgcn_global_load_lds(
        (const __attribute__((address_space(1))) void*)gsrc,
        (__attribute__((address_space(3))) void*)ldst,
        16, 0, 0);
}

#define CFENCE() asm volatile("" ::: "memory")
#define BARRIER() { CFENCE(); __builtin_amdgcn_s_barrier(); CFENCE(); }

// --- 1. column L2 norms: inv = QSCALE/(||col|| + eps); one thread per column ---
__global__ void norm_kernel(const float* __restrict__ x, const float* __restrict__ s,
                            float* __restrict__ invx, float* __restrict__ invs) {
    const float* src = blockIdx.y == 0 ? x : s;
    float* dst = (blockIdx.y == 0) ? invx : invs;
    int j = blockIdx.x * 256 + threadIdx.x;        // 0..16383
    float sum = 0.f;
    for (int c = 0; c < C_DIM; ++c) {
        float v = src[(size_t)c * P_DIM + j];
        sum += v * v;
    }
    dst[j] = QSCALE / (sqrtf(sum) + EPSF);
}

// --- 2. transpose, normalize*256, round to int8 ---
// Sn (z=1): row-major [p][c] (DMA->LDS path).
// Xn (z=0): fragment-linear for direct global->VGPR MFMA A-operands:
//   byte addr = (((kt*1024 + g)*2 + ks)<<10) + lane*16 + (kb&15),
//   g = row>>4, lane = (kb>>4)*16 + (row&15). 1KB per (kt,g,ks) = one wave's
//   coalesced global_load_dwordx4. Verified (R11 absmax 0.0).
__global__ void tnorm_kernel(const float* __restrict__ x, const float* __restrict__ s,
                             const float* __restrict__ invx, const float* __restrict__ invs,
                             u8* __restrict__ Xn, u8* __restrict__ Sn) {
    __shared__ float tile[64][65];
    const float* src = blockIdx.z ? s : x;
    const float* inv = blockIdx.z ? invs : invx;
    u8* dst = blockIdx.z ? Sn : Xn;
    int c0 = blockIdx.y * 64;
    int j0 = blockIdx.x * 64;
    int t = threadIdx.x;
    #pragma unroll
    for (int it = 0; it < 16; ++it) {
        int idx = it * 256 + t;
        int cr = idx >> 6, jc = idx & 63;
        tile[cr][jc] = src[(c0 + cr) * P_DIM + j0 + jc];
    }
    __syncthreads();
    const int kt = c0 >> 7;
    const int ks = (c0 >> 6) & 1;
    #pragma unroll
    for (int it = 0; it < 2; ++it) {
        int item = it * 256 + t;
        int jr = item >> 3;
        int oct = item & 7;
        float iv = inv[j0 + jr];
        unsigned long long pk = 0;
        #pragma unroll
        for (int o = 0; o < 8; ++o) {
            float v = tile[oct * 8 + o][jr] * iv;
            v = fminf(fmaxf(v, -127.0f), 127.0f);
            int q = (int)rintf(v);
            pk |= ((unsigned long long)(unsigned)(q & 0xFF)) << (8 * o);
        }
        size_t addr;
        if (blockIdx.z) {
            addr = (size_t)(j0 + jr) * C_DIM + c0 + oct * 8;
        } else {
            const int g = (j0 + jr) >> 4;
            const int lane = ((oct >> 1) << 4) + (jr & 15);
            addr = ((((size_t)kt * 1024 + g) * 2 + ks) << 10) + lane * 16 + ((oct & 1) << 3);
        }
        *(unsigned long long*)(dst + addr) = pk;
    }
}

// --- 3. 128x128-tile i8 GEMM: A direct from L2, B via LDS; 2 blocks/CU ---
// XCD map (R10-proven): xcd=bid&7 owns iblks [16x,16x+16) x all 4 splits
// -> A 1.5MB/XCD L2-resident. Phase t: {ds_read bF | 8 A(t) b128 loads |
// DMA B(t+2)->live buf | vmcnt(4) lgkmcnt(0) | 32 MFMA | barrier}.
__global__ __launch_bounds__(256, 2) void nnfm_gemm_max(
    const u8* __restrict__ Xn, const u8* __restrict__ Sn,
    float* __restrict__ wmax) {
    __shared__ __align__(16) u8 smB[2][128 * 128];

    const int bid = blockIdx.x;
    const int xcd = bid & 7;
    const int idx = bid >> 3;               // 0..63
    const int iblk = xcd * 16 + (idx & 15);
    const int split = idx >> 4;             // 0..3
    const int i0 = iblk * 128;
    const int jbase = split * (P_DIM / JSPLIT);

    const int tid = threadIdx.x;
    const int lane = tid & 63;
    const int wid = tid >> 6;
    const int wrow = (wid >> 1) * 64;
    const int wcol = (wid & 1) * 64;
    const int lm = lane & 15;

    const int srow = wid * 8 + (lane >> 3);                // staging row (+c*32)
    const int scol = ((lane & 7) ^ (lane >> 3)) * 16;      // swizzled source col
    const int kidx0 = (((lane >> 4) + 0) ^ (lane & 7)) * 16;
    const int kidx1 = (((lane >> 4) + 4) ^ (lane & 7)) * 16;

    // A fragment base: g = iblk*8 + wrow/16 + m ; addr = ((kt*1024+g)*2+ks)<<10 + lane*16
    const u8* Abase = Xn + ((((size_t)iblk * 8 + (wrow >> 4)) * 2) << 10) + lane * 16;

#define STAGE_B(jt_t, kk_t, buf_t) { \
    _Pragma("unroll") \
    for (int c = 0; c < 4; ++c) \
      async_copy16(Sn + (size_t)(jbase + (jt_t) * 128 + c * 32 + srow) * C_DIM + (kk_t) * 128 + scol, \
                   &smB[buf_t][(c * 32 + wid * 8) * 128]); }

#define RD_B(BUF) { \
    _Pragma("unroll") \
    for (int n = 0; n < 4; ++n) { \
      bF[n][0] = *(const i32x4*)&smB[BUF][(wcol + n * 16 + lm) * 128 + kidx0]; \
      bF[n][1] = *(const i32x4*)&smB[BUF][(wcol + n * 16 + lm) * 128 + kidx1]; \
    } }

#define LD_A(kt_t) { \
    _Pragma("unroll") \
    for (int m = 0; m < 4; ++m) { \
      aF[m][0] = *(const i32x4*)(Abase + ((((size_t)(kt_t) * 1024 + m) * 2 + 0) << 10)); \
      aF[m][1] = *(const i32x4*)(Abase + ((((size_t)(kt_t) * 1024 + m) * 2 + 1) << 10)); \
    } }

#define MFMA32(DOZERO) { \
    if (DOZERO) { \
      _Pragma("unroll") \
      for (int m = 0; m < 4; ++m) \
        _Pragma("unroll") \
        for (int n = 0; n < 4; ++n) \
          acc[m][n] = i32x4{0, 0, 0, 0}; \
    } \
    __builtin_amdgcn_s_setprio(1); \
    _Pragma("unroll") \
    for (int ks = 0; ks < 2; ++ks) \
      _Pragma("unroll") \
      for (int m = 0; m < 4; ++m) \
        _Pragma("unroll") \
        for (int n = 0; n < 4; ++n) \
          acc[m][n] = __builtin_amdgcn_mfma_i32_16x16x64_i8(aF[m][ks], bF[n][ks], acc[m][n], 0, 0, 0); \
    __builtin_amdgcn_s_setprio(0); }

    i32x4 acc[4][4];
    int rmax[4][4];
    i32x4 aF[4][2], bF[4][2];
    #pragma unroll
    for (int m = 0; m < 4; ++m)
        #pragma unroll
        for (int r = 0; r < 4; ++r) rmax[m][r] = (int)0x80000000;

    // prologue: B(0)->buf0, B(1)->buf1 (8 DMA); drain B(0) -> vmcnt(4)
    STAGE_B(0, 0, 0);
    STAGE_B(0, 1, 1);
    asm volatile("s_waitcnt vmcnt(4)" ::: "memory");
    BARRIER();

    for (int jt = 0; jt < NJT; ++jt) {
        for (int kk = 0; kk < KT; ++kk) {
            const int buf = kk & 1;
            int kk2 = kk + 2, jt2 = jt;
            if (kk2 >= KT) { kk2 -= KT; jt2 = (jt + 1) & (NJT - 1); }
            const bool z = (kk == 0), rx = (kk == KT - 1);

            RD_B(buf)
            LD_A(kk)
            STAGE_B(jt2, kk2, buf)            // into live buf after its reads
            asm volatile("s_waitcnt vmcnt(4) lgkmcnt(0)" ::: "memory");
            MFMA32(z)
            if (rx) {
                #pragma unroll
                for (int m = 0; m < 4; ++m)
                    #pragma unroll
                    for (int r = 0; r < 4; ++r) {
                        int mx = acc[m][0][r];
                        #pragma unroll
                        for (int n = 1; n < 4; ++n)
                            if (acc[m][n][r] > mx) mx = acc[m][n][r];
                        if (mx > rmax[m][r]) rmax[m][r] = mx;
                    }
            }
            BARRIER();
        }
    }

    // epilogue: drain all in-flight ops before reusing LDS
    asm volatile("s_waitcnt vmcnt(0) lgkmcnt(0)" ::: "memory");
    BARRIER();

    const float isc = 1.0f / (QSCALE * QSCALE);
    float* red = (float*)&smB[0][0];   // [2 col-waves][128 rows]
    #pragma unroll
    for (int m = 0; m < 4; ++m)
        #pragma unroll
        for (int r = 0; r < 4; ++r) {
            int v = rmax[m][r];
            int o;
            o = __shfl_xor(v, 1); if (o > v) v = o;
            o = __shfl_xor(v, 2); if (o > v) v = o;
            o = __shfl_xor(v, 4); if (o > v) v = o;
            o = __shfl_xor(v, 8); if (o > v) v = o;
            if (lm == 0) {
                const int row_l = wrow + m * 16 + (lane >> 4) * 4 + r;
                red[(wid & 1) * 128 + row_l] = (float)v * isc;
            }
        }
    BARRIER();
    if (tid < 128) {
        wmax[(size_t)split * P_DIM + i0 + tid] = fmaxf(red[tid], red[128 + tid]);
    }
}

// --- 4. loss = mean(1 - max over 4 partials) ---
__global__ void final_reduce(const float* __restrict__ wmax, float* __restrict__ out) {
    __shared__ float red[256];
    int t = threadIdx.x;
    float sum = 0.f;
    for (int i = t; i < P_DIM; i += 256) {
        float m = wmax[i];
        #pragma unroll
        for (int sp = 1; sp < 4; ++sp) m = fmaxf(m, wmax[(size_t)sp * P_DIM + i]);
        sum += 1.0f - m;
    }
    red[t] = sum;
    __syncthreads();
    for (int st = 128; st > 0; st >>= 1) {
        if (t < st) red[t] += red[t + st];
        __syncthreads();
    }
    if (t == 0) out[0] = red[0] * (1.0f / (float)P_DIM);
}

extern "C" void kernel_launch(void* const* d_in, const int* in_sizes, int n_in,
                              void* d_out, int out_size, void* d_ws, size_t ws_size,
                              hipStream_t stream) {
    const float* x = (const float*)d_in[0];
    const float* s = (const float*)d_in[1];
    float* out = (float*)d_out;
    char* ws = (char*)d_ws;

    u8* Xn = (u8*)(ws + OFF_XN);
    u8* Sn = (u8*)(ws + OFF_SN);
    float* invx = (float*)(ws + OFF_INVX);
    float* invs = (float*)(ws + OFF_INVS);
    float* wmax = (float*)(ws + OFF_MAX);

    norm_kernel<<<dim3(64, 2), 256, 0, stream>>>(x, s, invx, invs);
    tnorm_kernel<<<dim3(256, 12, 2), 256, 0, stream>>>(x, s, invx, invs, Xn, Sn);
    nnfm_gemm_max<<<dim3((P_DIM / 128) * JSPLIT), 256, 0, stream>>>(Xn, Sn, wmax);
    final_reduce<<<1, 256, 0, stream>>>(wmax, out);
}